// Round 8
// baseline (552.018 us; speedup 1.0000x reference)
//
#include <hip/hip_runtime.h>
#include <hip/hip_cooperative_groups.h>
#include <math.h>

namespace cg = cooperative_groups;

#define NN 10000
#define EE 160000
#define DIM 256
#define KK 512            // concatenated K = 2*DIM
#define CAP 64            // bucket capacity = wavefront size: slot list in 1 per-lane load
#define EPS_BN 1e-5f
#define AST 516           // LDS A-tile row stride in shorts (1032 B = 8B-aligned, 2-way banks)
#define BLK 512

typedef __attribute__((ext_vector_type(8)))  short bf16x8;
typedef __attribute__((ext_vector_type(16))) float f32x16;

union U16 { uint2 u2[2]; bf16x8 v; };

static __device__ __forceinline__ unsigned short f2bf(float f) {
    unsigned u = __float_as_uint(f);
    unsigned r = (u + 0x7fffu + ((u >> 16) & 1u)) >> 16;   // RTNE
    return (unsigned short)r;
}
static __device__ __forceinline__ float bflo(unsigned v) { return __uint_as_float(v << 16); }
static __device__ __forceinline__ float bfhi(unsigned v) { return __uint_as_float(v & 0xffff0000u); }
static __device__ __forceinline__ unsigned packbf(float a, float b) {
    return (unsigned)f2bf(a) | ((unsigned)f2bf(b) << 16);
}

struct Params {
    const float* x; const int* src; const int* dst;
    const float *Ws0, *Wn0, *Ws1, *Wn1, *Ws2, *Wn2;
    const float *g0, *be0, *g1, *be1, *g2, *be2;
    float* out;
    unsigned short* hx;     // [NN][DIM] bf16 x (input of L0)
    unsigned short* z0;     // [NN][DIM] bf16 raw z ping
    unsigned short* z1;     // [NN][DIM] bf16 raw z pong
    unsigned short* hn;     // [NN][DIM] bf16 pre-normalized h (fallback path only)
    unsigned short* magg;   // [NN][DIM] bf16 neighbor-mean of normalized h
    unsigned short* wcat;   // [3][DIM][KK] bf16, [n][k]
    float* stats;           // [3][2*DIM]
    int* cnt;               // [NN]
    int* slots;             // [NN][CAP]
};

static __device__ __forceinline__ void accum8(float* a, uint4 v) {
    a[0] += bflo(v.x); a[1] += bfhi(v.x);
    a[2] += bflo(v.y); a[3] += bfhi(v.y);
    a[4] += bflo(v.z); a[5] += bfhi(v.z);
    a[6] += bflo(v.w); a[7] += bfhi(v.w);
}
static __device__ __forceinline__ void accum8n(float* a, uint4 v,
                                               const float* sc, const float* sh) {
    a[0] += fmaxf(bflo(v.x) * sc[0] + sh[0], 0.f);
    a[1] += fmaxf(bfhi(v.x) * sc[1] + sh[1], 0.f);
    a[2] += fmaxf(bflo(v.y) * sc[2] + sh[2], 0.f);
    a[3] += fmaxf(bfhi(v.y) * sc[3] + sh[3], 0.f);
    a[4] += fmaxf(bflo(v.z) * sc[4] + sh[4], 0.f);
    a[5] += fmaxf(bfhi(v.z) * sc[5] + sh[5], 0.f);
    a[6] += fmaxf(bflo(v.w) * sc[6] + sh[6], 0.f);
    a[7] += fmaxf(bfhi(v.w) * sc[7] + sh[7], 0.f);
}

// ============================================================================
// Mega-kernel (R18): R17 structure, but grid-size-agnostic (all strides use
// gridDim.x) so the host can size the grid from the occupancy query. R17's
// failure mode was a silently-dropped hipErrorCooperativeLaunchTooLarge.
// Phases: prep | bucket | 3x(gather | gemm) | norm, 8 grid.sync() total.
// ============================================================================
__global__ __launch_bounds__(BLK, 4) void k_mega(Params P) {
    cg::grid_group grid = cg::this_grid();
    __shared__ unsigned short At[32][AST];                  // 33 KB (gemm phase)
    const int t = threadIdx.x;
    const int bid = blockIdx.x;
    const int nblk = gridDim.x;
    const int gtid = bid * BLK + t;
    const int gstride = nblk * BLK;
    const int wave = t >> 6, lane = t & 63;
    const int h = lane >> 5, l = lane & 31;

    // ================= phase 0: prep (converts + zeroing) =================
    for (int g = gtid; g < NN * 64; g += gstride) {         // x -> hx bf16
        int r = g >> 6, c4 = (g & 63) * 4;
        float4 v = *(const float4*)(P.x + (size_t)r * DIM + c4);
        uint2 p; p.x = packbf(v.x, v.y); p.y = packbf(v.z, v.w);
        *(uint2*)(P.hx + (size_t)r * DIM + c4) = p;
    }
    for (int g = gtid; g < 3 * DIM * KK; g += gstride) {    // [Ws;Wn] -> wcat [n][k]
        int L = g >> 17; int i = g & 131071;
        int k = i >> 8, n = i & 255;
        const float* Ws = (L == 0) ? P.Ws0 : ((L == 1) ? P.Ws1 : P.Ws2);
        const float* Wn = (L == 0) ? P.Wn0 : ((L == 1) ? P.Wn1 : P.Wn2);
        float v = (k < DIM) ? Ws[(size_t)k * DIM + n] : Wn[(size_t)(k - DIM) * DIM + n];
        P.wcat[(size_t)L * DIM * KK + (size_t)n * KK + k] = f2bf(v);
    }
    for (int g = gtid; g < NN + 6 * DIM; g += gstride) {
        if (g < NN) P.cnt[g] = 0;
        else P.stats[g - NN] = 0.f;
    }
    grid.sync();

    // ================= phase 1: bucket build =================
    for (int e = gtid; e < EE; e += gstride) {
        int d = P.dst[e];
        int p = atomicAdd(&P.cnt[d], 1);
        if (p < CAP) P.slots[(size_t)d * CAP + p] = P.src[e];
    }
    grid.sync();

    // ================= layers =================
    for (int L = 0; L < 3; ++L) {
        const unsigned short* src = (L == 0) ? P.hx : ((L == 1) ? P.z0 : P.z1);
        unsigned short* dst = (L == 0) ? P.z0 : ((L == 1) ? P.z1 : P.z0);
        const float* gam = (L == 1) ? P.g0 : P.g1;          // L>0 only
        const float* bet = (L == 1) ? P.be0 : P.be1;
        const float* stp = P.stats + (L - 1) * 2 * DIM;     // L>0 only

        // ---- BN affine for cols l*8..l*8+7 (gather, per-edge normalize) ----
        float sc[8], sh[8];
        if (L > 0) {
#pragma unroll
            for (int i = 0; i < 8; ++i) {
                int c = l * 8 + i;
                float mu  = stp[c] * (1.0f / NN);
                float var = stp[DIM + c] * (1.0f / NN) - mu * mu;
                float k = rsqrtf(var + EPS_BN) * gam[c];
                sc[i] = k;
                sh[i] = bet[c] - mu * k;
            }
        }

        // -------- gather phase: wave-per-node, grid-stride over nodes --------
        // All __shfl in wave-uniform flow (R12 lesson: ds_bpermute from
        // inactive lanes is undefined). No early return before grid.sync.
        {
            const uint4* srcm = (const uint4*)src;
            int wid = bid * 8 + wave;
            for (int node = wid; node < NN; node += nblk * 8) {
                int cnt = P.cnt[node]; if (cnt > CAP) cnt = CAP;
                int sv = P.slots[(size_t)node * CAP + lane];
                float a[8] = {0, 0, 0, 0, 0, 0, 0, 0};
                int j = 0;                                  // UNIFORM loop var
                for (; j + 15 < cnt; j += 16) {             // 8 loads/half in flight
                    int r0 = __shfl(sv, j +  0 + h), r1 = __shfl(sv, j +  2 + h);
                    int r2 = __shfl(sv, j +  4 + h), r3 = __shfl(sv, j +  6 + h);
                    int r4 = __shfl(sv, j +  8 + h), r5 = __shfl(sv, j + 10 + h);
                    int r6 = __shfl(sv, j + 12 + h), r7 = __shfl(sv, j + 14 + h);
                    uint4 v0 = srcm[(size_t)r0 * 32 + l];
                    uint4 v1 = srcm[(size_t)r1 * 32 + l];
                    uint4 v2 = srcm[(size_t)r2 * 32 + l];
                    uint4 v3 = srcm[(size_t)r3 * 32 + l];
                    uint4 v4 = srcm[(size_t)r4 * 32 + l];
                    uint4 v5 = srcm[(size_t)r5 * 32 + l];
                    uint4 v6 = srcm[(size_t)r6 * 32 + l];
                    uint4 v7 = srcm[(size_t)r7 * 32 + l];
                    if (L == 0) {
                        accum8(a, v0); accum8(a, v1); accum8(a, v2); accum8(a, v3);
                        accum8(a, v4); accum8(a, v5); accum8(a, v6); accum8(a, v7);
                    } else {
                        accum8n(a, v0, sc, sh); accum8n(a, v1, sc, sh);
                        accum8n(a, v2, sc, sh); accum8n(a, v3, sc, sh);
                        accum8n(a, v4, sc, sh); accum8n(a, v5, sc, sh);
                        accum8n(a, v6, sc, sh); accum8n(a, v7, sc, sh);
                    }
                }
                for (; j + 3 < cnt; j += 4) {
                    int r0 = __shfl(sv, j + h), r1 = __shfl(sv, j + 2 + h);
                    uint4 v0 = srcm[(size_t)r0 * 32 + l];
                    uint4 v1 = srcm[(size_t)r1 * 32 + l];
                    if (L == 0) { accum8(a, v0); accum8(a, v1); }
                    else { accum8n(a, v0, sc, sh); accum8n(a, v1, sc, sh); }
                }
                for (; j + 1 < cnt; j += 2) {
                    int r0 = __shfl(sv, j + h);
                    uint4 v0 = srcm[(size_t)r0 * 32 + l];
                    if (L == 0) accum8(a, v0); else accum8n(a, v0, sc, sh);
                }
                if (j < cnt) {                              // odd leftover, uniform shfl
                    int r0 = __shfl(sv, cnt - 1);
                    uint4 v0 = srcm[(size_t)r0 * 32 + l];
                    if (h == 0) {
                        if (L == 0) accum8(a, v0); else accum8n(a, v0, sc, sh);
                    }
                }
#pragma unroll
                for (int q = 0; q < 8; ++q) a[q] += __shfl_xor(a[q], 32);
                if (h == 0) {
                    float inv = 1.0f / (float)(cnt > 1 ? cnt : 1);
                    uint4 o;
                    o.x = packbf(a[0] * inv, a[1] * inv);
                    o.y = packbf(a[2] * inv, a[3] * inv);
                    o.z = packbf(a[4] * inv, a[5] * inv);
                    o.w = packbf(a[6] * inv, a[7] * inv);
                    ((uint4*)P.magg)[(size_t)node * 32 + l] = o;
                }
            }
        }
        grid.sync();

        // -------- gemm phase: 313 tiles of 32 rows, grid-stride --------
        {
            int cgS = t & 31, rs = t >> 5;                  // col-group, row-slot
            float scg[8], shg[8];
            if (L > 0) {
#pragma unroll
                for (int i = 0; i < 8; ++i) {
                    int c = cgS * 8 + i;
                    float mu  = stp[c] * (1.0f / NN);
                    float var = stp[DIM + c] * (1.0f / NN) - mu * mu;
                    float k = rsqrtf(var + EPS_BN) * gam[c];
                    scg[i] = k;
                    shg[i] = bet[c] - mu * k;
                }
            }
            const unsigned short* wcatL = P.wcat + (size_t)L * DIM * KK;
            float* statsL = P.stats + L * 2 * DIM;
            for (int tile = bid; tile < 313; tile += nblk) {
                // ---- stage A-tile: thread = (row-slot rs, 8-col group cgS) ----
#pragma unroll
                for (int rr = 0; rr < 2; ++rr) {
                    int r = rs + rr * 16;
                    int node = tile * 32 + r;
                    unsigned short* arow = &At[r][0];
                    if (node < NN) {
                        uint4 ov = *(const uint4*)(src + (size_t)node * DIM + cgS * 8);
                        if (L > 0) {
                            uint4 o;
                            o.x = packbf(fmaxf(bflo(ov.x) * scg[0] + shg[0], 0.f),
                                         fmaxf(bfhi(ov.x) * scg[1] + shg[1], 0.f));
                            o.y = packbf(fmaxf(bflo(ov.y) * scg[2] + shg[2], 0.f),
                                         fmaxf(bfhi(ov.y) * scg[3] + shg[3], 0.f));
                            o.z = packbf(fmaxf(bflo(ov.z) * scg[4] + shg[4], 0.f),
                                         fmaxf(bfhi(ov.z) * scg[5] + shg[5], 0.f));
                            o.w = packbf(fmaxf(bflo(ov.w) * scg[6] + shg[6], 0.f),
                                         fmaxf(bfhi(ov.w) * scg[7] + shg[7], 0.f));
                            ov = o;
                        }
                        *(uint2*)(arow + cgS * 8)     = make_uint2(ov.x, ov.y);
                        *(uint2*)(arow + cgS * 8 + 4) = make_uint2(ov.z, ov.w);
                        uint4 mv = *(const uint4*)(P.magg + (size_t)node * DIM + cgS * 8);
                        *(uint2*)(arow + 256 + cgS * 8)     = make_uint2(mv.x, mv.y);
                        *(uint2*)(arow + 256 + cgS * 8 + 4) = make_uint2(mv.z, mv.w);
                    } else {
                        uint2 z2 = make_uint2(0u, 0u);
                        *(uint2*)(arow + cgS * 8)           = z2;
                        *(uint2*)(arow + cgS * 8 + 4)       = z2;
                        *(uint2*)(arow + 256 + cgS * 8)     = z2;
                        *(uint2*)(arow + 256 + cgS * 8 + 4) = z2;
                    }
                }
                __syncthreads();
                // ---- phase B: one 32x32x16 MFMA chain per wave ----
                int m = l;
                int row0 = tile * 32;
                int colw0 = wave * 32;                      // 8 waves x 32 = 256 cols
                const unsigned short* Bp = wcatL + (size_t)(colw0 + m) * KK + h * 8;
                const unsigned short* Arow = &At[m][0];
                f32x16 acc;
#pragma unroll
                for (int i = 0; i < 16; ++i) acc[i] = 0.f;
#pragma unroll 8
                for (int k0 = 0; k0 < KK; k0 += 16) {
                    U16 ua;
                    ua.u2[0] = *(const uint2*)(Arow + k0 + h * 8);
                    ua.u2[1] = *(const uint2*)(Arow + k0 + h * 8 + 4);
                    bf16x8 av = ua.v;
                    bf16x8 bv = *(const bf16x8*)(Bp + k0);
                    acc = __builtin_amdgcn_mfma_f32_32x32x16_bf16(av, bv, acc, 0, 0, 0);
                }
                int cc = colw0 + m;
                float s = 0.f, s2 = 0.f;
#pragma unroll
                for (int reg = 0; reg < 16; ++reg) {
                    int r = row0 + (reg & 3) + 8 * (reg >> 2) + 4 * h;
                    if (r < NN) {
                        float v = acc[reg];
                        dst[(size_t)r * DIM + cc] = f2bf(v);
                        s += v; s2 += v * v;
                    }
                }
                s  += __shfl_down(s, 32);
                s2 += __shfl_down(s2, 32);
                if (h == 0) {
                    atomicAdd(&statsL[cc], s);
                    atomicAdd(&statsL[DIM + cc], s2);
                }
                __syncthreads();                            // LDS safe for next tile
            }
        }
        grid.sync();
    }

    // ================= final: BN + sigmoid -> out (fp32) =================
    {
        const float* statsL = P.stats + 2 * 2 * DIM;
        for (int g = gtid; g < NN * 32; g += gstride) {
            int r = g >> 5, c8 = (g & 31) * 8;
            float f[8];
            uint4 v = *(const uint4*)(P.z0 + (size_t)r * DIM + c8);
            f[0] = bflo(v.x); f[1] = bfhi(v.x); f[2] = bflo(v.y); f[3] = bfhi(v.y);
            f[4] = bflo(v.z); f[5] = bfhi(v.z); f[6] = bflo(v.w); f[7] = bfhi(v.w);
#pragma unroll
            for (int i = 0; i < 8; ++i) {
                int c = c8 + i;
                float mu  = statsL[c] * (1.0f / NN);
                float var = statsL[DIM + c] * (1.0f / NN) - mu * mu;
                float k = rsqrtf(var + EPS_BN) * P.g2[c];
                float z = f[i] * k + (P.be2[c] - mu * k);
                f[i] = 1.0f / (1.0f + __expf(-z));
            }
            float4 o0 = make_float4(f[0], f[1], f[2], f[3]);
            float4 o1 = make_float4(f[4], f[5], f[6], f[7]);
            *(float4*)(P.out + (size_t)r * DIM + c8)     = o0;
            *(float4*)(P.out + (size_t)r * DIM + c8 + 4) = o1;
        }
    }
}

// ============================================================================
// Fallback pipeline (verbatim R15, passed at 220.0 us / absmax 0.0078):
// used if the cooperative launch is rejected.
// ============================================================================
__global__ __launch_bounds__(256) void k_prep(Params P) {
    int g0 = blockIdx.x * 256 + threadIdx.x;
    int stride = gridDim.x * 256;
    for (int g = g0; g < NN * 64; g += stride) {
        int r = g >> 6, c4 = (g & 63) * 4;
        float4 v = *(const float4*)(P.x + (size_t)r * DIM + c4);
        uint2 p; p.x = packbf(v.x, v.y); p.y = packbf(v.z, v.w);
        *(uint2*)(P.hx + (size_t)r * DIM + c4) = p;
    }
    for (int g = g0; g < 3 * DIM * KK; g += stride) {
        int L = g >> 17; int i = g & 131071;
        int k = i >> 8, n = i & 255;
        const float* Ws = (L == 0) ? P.Ws0 : ((L == 1) ? P.Ws1 : P.Ws2);
        const float* Wn = (L == 0) ? P.Wn0 : ((L == 1) ? P.Wn1 : P.Wn2);
        float v = (k < DIM) ? Ws[(size_t)k * DIM + n] : Wn[(size_t)(k - DIM) * DIM + n];
        P.wcat[(size_t)L * DIM * KK + (size_t)n * KK + k] = f2bf(v);
    }
    for (int g = g0; g < NN + 6 * DIM; g += stride) {
        if (g < NN) P.cnt[g] = 0;
        else P.stats[g - NN] = 0.f;
    }
}

__global__ __launch_bounds__(256) void k_bucket(Params P) {
    int e = blockIdx.x * 256 + threadIdx.x;
    if (e < EE) {
        int d = P.dst[e];
        int p = atomicAdd(&P.cnt[d], 1);
        if (p < CAP) P.slots[(size_t)d * CAP + p] = P.src[e];
    }
}

__global__ __launch_bounds__(256) void k_pre(Params P, int Lprev,
                                             const unsigned short* __restrict__ z,
                                             unsigned short* __restrict__ hn) {
    const float* st  = P.stats + Lprev * 2 * DIM;
    const float* gam = (Lprev == 0) ? P.g0 : P.g1;
    const float* bet = (Lprev == 0) ? P.be0 : P.be1;
    int t = threadIdx.x;
    int c8 = (t & 31) * 8;
    int r = blockIdx.x * 8 + (t >> 5);
    float sc[8], sh[8];
#pragma unroll
    for (int i = 0; i < 8; ++i) {
        int c = c8 + i;
        float mu  = st[c] * (1.0f / NN);
        float var = st[DIM + c] * (1.0f / NN) - mu * mu;
        float k = rsqrtf(var + EPS_BN) * gam[c];
        sc[i] = k;
        sh[i] = bet[c] - mu * k;
    }
    uint4 v = *(const uint4*)(z + (size_t)r * DIM + c8);
    uint4 o;
    o.x = packbf(fmaxf(bflo(v.x) * sc[0] + sh[0], 0.f),
                 fmaxf(bfhi(v.x) * sc[1] + sh[1], 0.f));
    o.y = packbf(fmaxf(bflo(v.y) * sc[2] + sh[2], 0.f),
                 fmaxf(bfhi(v.y) * sc[3] + sh[3], 0.f));
    o.z = packbf(fmaxf(bflo(v.z) * sc[4] + sh[4], 0.f),
                 fmaxf(bfhi(v.z) * sc[5] + sh[5], 0.f));
    o.w = packbf(fmaxf(bflo(v.w) * sc[6] + sh[6], 0.f),
                 fmaxf(bfhi(v.w) * sc[7] + sh[7], 0.f));
    *(uint4*)(hn + (size_t)r * DIM + c8) = o;
}

__global__ __launch_bounds__(256) void k_gather(Params P,
                                                const unsigned short* __restrict__ hsrc,
                                                unsigned short* __restrict__ magg) {
    int t = threadIdx.x;
    int wave = t >> 6, lane = t & 63;
    int h = lane >> 5, l = lane & 31;
    int node = blockIdx.x * 4 + wave;
    if (node >= NN) return;
    int cnt = P.cnt[node]; if (cnt > CAP) cnt = CAP;
    int sv = P.slots[(size_t)node * CAP + lane];
    const uint4* srcm = (const uint4*)hsrc;
    float a[8] = {0, 0, 0, 0, 0, 0, 0, 0};
    int j = 0;
    for (; j + 15 < cnt; j += 16) {
        int r0 = __shfl(sv, j +  0 + h), r1 = __shfl(sv, j +  2 + h);
        int r2 = __shfl(sv, j +  4 + h), r3 = __shfl(sv, j +  6 + h);
        int r4 = __shfl(sv, j +  8 + h), r5 = __shfl(sv, j + 10 + h);
        int r6 = __shfl(sv, j + 12 + h), r7 = __shfl(sv, j + 14 + h);
        uint4 v0 = srcm[(size_t)r0 * 32 + l];
        uint4 v1 = srcm[(size_t)r1 * 32 + l];
        uint4 v2 = srcm[(size_t)r2 * 32 + l];
        uint4 v3 = srcm[(size_t)r3 * 32 + l];
        uint4 v4 = srcm[(size_t)r4 * 32 + l];
        uint4 v5 = srcm[(size_t)r5 * 32 + l];
        uint4 v6 = srcm[(size_t)r6 * 32 + l];
        uint4 v7 = srcm[(size_t)r7 * 32 + l];
        accum8(a, v0); accum8(a, v1); accum8(a, v2); accum8(a, v3);
        accum8(a, v4); accum8(a, v5); accum8(a, v6); accum8(a, v7);
    }
    for (; j + 3 < cnt; j += 4) {
        int r0 = __shfl(sv, j + h), r1 = __shfl(sv, j + 2 + h);
        uint4 v0 = srcm[(size_t)r0 * 32 + l];
        uint4 v1 = srcm[(size_t)r1 * 32 + l];
        accum8(a, v0); accum8(a, v1);
    }
    for (; j + 1 < cnt; j += 2) {
        int r0 = __shfl(sv, j + h);
        uint4 v0 = srcm[(size_t)r0 * 32 + l];
        accum8(a, v0);
    }
    if (j < cnt) {
        int r0 = __shfl(sv, cnt - 1);
        uint4 v0 = srcm[(size_t)r0 * 32 + l];
        if (h == 0) accum8(a, v0);
    }
#pragma unroll
    for (int q = 0; q < 8; ++q) a[q] += __shfl_xor(a[q], 32);
    if (h == 0) {
        float inv = 1.0f / (float)(cnt > 1 ? cnt : 1);
        uint4 o;
        o.x = packbf(a[0] * inv, a[1] * inv);
        o.y = packbf(a[2] * inv, a[3] * inv);
        o.z = packbf(a[4] * inv, a[5] * inv);
        o.w = packbf(a[6] * inv, a[7] * inv);
        ((uint4*)magg)[(size_t)node * 32 + l] = o;
    }
}

__global__ __launch_bounds__(512) void k_gemm(Params P, int L,
                                              const unsigned short* __restrict__ hsrc,
                                              const unsigned short* __restrict__ magg,
                                              unsigned short* __restrict__ gdst) {
    __shared__ unsigned short At[32][AST];
    int t = threadIdx.x;
    int wave = t >> 6, lane = t & 63;
    int h = lane >> 5, l = lane & 31;
    {
        int r = t >> 4, q = t & 15;
        int node = blockIdx.x * 32 + r;
        const unsigned short* srcp = (q < 8) ? hsrc : magg;
        int c0 = (q & 7) * 32;
        unsigned short* dstp = &At[r][(q < 8 ? 0 : 256) + c0];
        if (node < NN) {
            const uint4* gp = (const uint4*)(srcp + (size_t)node * DIM + c0);
            uint4 v0 = gp[0], v1 = gp[1], v2 = gp[2], v3 = gp[3];
            *(uint2*)(dstp)      = make_uint2(v0.x, v0.y);
            *(uint2*)(dstp + 4)  = make_uint2(v0.z, v0.w);
            *(uint2*)(dstp + 8)  = make_uint2(v1.x, v1.y);
            *(uint2*)(dstp + 12) = make_uint2(v1.z, v1.w);
            *(uint2*)(dstp + 16) = make_uint2(v2.x, v2.y);
            *(uint2*)(dstp + 20) = make_uint2(v2.z, v2.w);
            *(uint2*)(dstp + 24) = make_uint2(v3.x, v3.y);
            *(uint2*)(dstp + 28) = make_uint2(v3.z, v3.w);
        } else {
            uint2 z = make_uint2(0u, 0u);
#pragma unroll
            for (int q8 = 0; q8 < 8; ++q8) *(uint2*)(dstp + q8 * 4) = z;
        }
    }
    __syncthreads();
    const unsigned short* wcatL = P.wcat + (size_t)L * DIM * KK;
    float* statsL = P.stats + L * 2 * DIM;
    int m = l;
    int row0 = blockIdx.x * 32;
    int colw0 = wave * 32;
    const unsigned short* Bp = wcatL + (size_t)(colw0 + m) * KK + h * 8;
    const unsigned short* Arow = &At[m][0];
    f32x16 acc;
#pragma unroll
    for (int i = 0; i < 16; ++i) acc[i] = 0.f;
#pragma unroll 8
    for (int k0 = 0; k0 < KK; k0 += 16) {
        U16 ua;
        ua.u2[0] = *(const uint2*)(Arow + k0 + h * 8);
        ua.u2[1] = *(const uint2*)(Arow + k0 + h * 8 + 4);
        bf16x8 av = ua.v;
        bf16x8 bv = *(const bf16x8*)(Bp + k0);
        acc = __builtin_amdgcn_mfma_f32_32x32x16_bf16(av, bv, acc, 0, 0, 0);
    }
    int cc = colw0 + m;
    float s = 0.f, s2 = 0.f;
#pragma unroll
    for (int reg = 0; reg < 16; ++reg) {
        int r = row0 + (reg & 3) + 8 * (reg >> 2) + 4 * h;
        if (r < NN) {
            float v = acc[reg];
            gdst[(size_t)r * DIM + cc] = f2bf(v);
            s += v; s2 += v * v;
        }
    }
    s  += __shfl_down(s, 32);
    s2 += __shfl_down(s2, 32);
    if (h == 0) {
        atomicAdd(&statsL[cc], s);
        atomicAdd(&statsL[DIM + cc], s2);
    }
}

__global__ __launch_bounds__(256) void k_norm(Params P) {
    const float* statsL = P.stats + 2 * 2 * DIM;
    int t = threadIdx.x;
    int c8 = (t & 31) * 8;
    int r = blockIdx.x * 8 + (t >> 5);
    float sc[8], sh[8];
#pragma unroll
    for (int i = 0; i < 8; ++i) {
        int c = c8 + i;
        float mu  = statsL[c] * (1.0f / NN);
        float var = statsL[DIM + c] * (1.0f / NN) - mu * mu;
        float k = rsqrtf(var + EPS_BN) * P.g2[c];
        sc[i] = k;
        sh[i] = P.be2[c] - mu * k;
    }
    uint4 v = *(const uint4*)(P.z0 + (size_t)r * DIM + c8);
    float f[8] = {bflo(v.x), bfhi(v.x), bflo(v.y), bfhi(v.y),
                  bflo(v.z), bfhi(v.z), bflo(v.w), bfhi(v.w)};
#pragma unroll
    for (int i = 0; i < 8; ++i) f[i] = f[i] * sc[i] + sh[i];
    float4 o0, o1;
    o0.x = 1.0f / (1.0f + __expf(-f[0]));
    o0.y = 1.0f / (1.0f + __expf(-f[1]));
    o0.z = 1.0f / (1.0f + __expf(-f[2]));
    o0.w = 1.0f / (1.0f + __expf(-f[3]));
    o1.x = 1.0f / (1.0f + __expf(-f[4]));
    o1.y = 1.0f / (1.0f + __expf(-f[5]));
    o1.z = 1.0f / (1.0f + __expf(-f[6]));
    o1.w = 1.0f / (1.0f + __expf(-f[7]));
    *(float4*)(P.out + (size_t)r * DIM + c8)     = o0;
    *(float4*)(P.out + (size_t)r * DIM + c8 + 4) = o1;
}

extern "C" void kernel_launch(void* const* d_in, const int* in_sizes, int n_in,
                              void* d_out, int out_size, void* d_ws, size_t ws_size,
                              hipStream_t stream) {
    Params P;
    P.x   = (const float*)d_in[0];
    P.src = (const int*)d_in[1];
    P.dst = (const int*)d_in[2];
    P.Ws0 = (const float*)d_in[3];  P.Wn0 = (const float*)d_in[4];
    P.g0  = (const float*)d_in[6];  P.be0 = (const float*)d_in[7];
    P.Ws1 = (const float*)d_in[8];  P.Wn1 = (const float*)d_in[9];
    P.g1  = (const float*)d_in[11]; P.be1 = (const float*)d_in[12];
    P.Ws2 = (const float*)d_in[13]; P.Wn2 = (const float*)d_in[14];
    P.g2  = (const float*)d_in[16]; P.be2 = (const float*)d_in[17];
    P.out = (float*)d_out;

    char* ws = (char*)d_ws;
    size_t off = 0;
    P.hx   = (unsigned short*)(ws + off); off += (size_t)NN * DIM * 2;       // 5.12 MB
    P.z0   = (unsigned short*)(ws + off); off += (size_t)NN * DIM * 2;       // 5.12 MB
    P.z1   = (unsigned short*)(ws + off); off += (size_t)NN * DIM * 2;       // 5.12 MB
    P.hn   = (unsigned short*)(ws + off); off += (size_t)NN * DIM * 2;       // 5.12 MB
    P.magg = (unsigned short*)(ws + off); off += (size_t)NN * DIM * 2;       // 5.12 MB
    P.wcat = (unsigned short*)(ws + off); off += (size_t)3 * DIM * KK * 2;   // 0.79 MB
    P.stats = (float*)(ws + off); off += 3 * 2 * DIM * sizeof(float);
    P.cnt   = (int*)(ws + off); off += (size_t)NN * 4; off = (off + 255) & ~(size_t)255;
    P.slots = (int*)(ws + off); off += (size_t)NN * CAP * 4;                 // 2.56 MB
    (void)ws_size;

    // ---- cooperative grid sizing: probe occupancy once (host-side, safe) ----
    static int coop_grid = -1;                 // -1 = unprobed, 0 = coop disabled
    if (coop_grid < 0) {
        int occ = 0;
        hipError_t e = hipOccupancyMaxActiveBlocksPerMultiprocessor(&occ, k_mega, BLK, 0);
        if (e != hipSuccess || occ < 1) { coop_grid = 0; (void)hipGetLastError(); }
        else coop_grid = (occ >= 2) ? 512 : 256;   // 256 CUs x blocks/CU
    }

    bool done = false;
    if (coop_grid > 0) {
        void* kargs[] = { (void*)&P };
        hipError_t e = hipLaunchCooperativeKernel(k_mega, dim3(coop_grid), dim3(BLK),
                                                  kargs, 0, stream);
        if (e == hipSuccess) done = true;
        else { (void)hipGetLastError(); coop_grid = 0; }   // disable for future calls
    }
    if (!done) {
        // R15 fallback pipeline (passed: 220 us, absmax 0.0078)
        k_prep<<<512, 256, 0, stream>>>(P);
        k_bucket<<<(EE + 255) / 256, 256, 0, stream>>>(P);
        k_gather<<<2500, 256, 0, stream>>>(P, P.hx, P.magg);
        k_gemm<<<313, 512, 0, stream>>>(P, 0, P.hx, P.magg, P.z0);
        k_pre<<<1250, 256, 0, stream>>>(P, 0, P.z0, P.hn);
        k_gather<<<2500, 256, 0, stream>>>(P, P.hn, P.magg);
        k_gemm<<<313, 512, 0, stream>>>(P, 1, P.hn, P.magg, P.z1);
        k_pre<<<1250, 256, 0, stream>>>(P, 1, P.z1, P.hn);
        k_gather<<<2500, 256, 0, stream>>>(P, P.hn, P.magg);
        k_gemm<<<313, 512, 0, stream>>>(P, 2, P.hn, P.magg, P.z0);
        k_norm<<<NN / 8, 256, 0, stream>>>(P);
    }
}

// Round 9
// 224.106 us; speedup vs baseline: 2.4632x; 2.4632x over previous
//
#include <hip/hip_runtime.h>
#include <hip/hip_cooperative_groups.h>
#include <math.h>

namespace cg = cooperative_groups;

#define NN 10000
#define EE 160000
#define DIM 256
#define KK 512            // concatenated K = 2*DIM
#define CAP 64            // bucket capacity = wavefront size: slot list in 1 per-lane load
#define EPS_BN 1e-5f
#define AST 516           // LDS A-tile row stride in shorts (1032 B = 8B-aligned, 2-way banks)
#define BLK 512

typedef __attribute__((ext_vector_type(8)))  short bf16x8;
typedef __attribute__((ext_vector_type(16))) float f32x16;

union U16 { uint2 u2[2]; bf16x8 v; };

static __device__ __forceinline__ unsigned short f2bf(float f) {
    unsigned u = __float_as_uint(f);
    unsigned r = (u + 0x7fffu + ((u >> 16) & 1u)) >> 16;   // RTNE
    return (unsigned short)r;
}
static __device__ __forceinline__ float bflo(unsigned v) { return __uint_as_float(v << 16); }
static __device__ __forceinline__ float bfhi(unsigned v) { return __uint_as_float(v & 0xffff0000u); }
static __device__ __forceinline__ unsigned packbf(float a, float b) {
    return (unsigned)f2bf(a) | ((unsigned)f2bf(b) << 16);
}

struct Params {
    const float* x; const int* src; const int* dst;
    const float *Ws0, *Wn0, *Ws1, *Wn1, *Ws2, *Wn2;
    const float *g0, *be0, *g1, *be1, *g2, *be2;
    float* out;
    unsigned short* hx;     // [NN][DIM] bf16 x (input of L0)
    unsigned short* z0;     // [NN][DIM] bf16 raw z ping
    unsigned short* z1;     // [NN][DIM] bf16 raw z pong
    unsigned short* hn;     // [NN][DIM] bf16 pre-normalized h (fallback path only)
    unsigned short* magg;   // [NN][DIM] bf16 neighbor-mean of normalized h
    unsigned short* wcat;   // [3][DIM][KK] bf16, [n][k]
    float* stats;           // [3][2*DIM]
    int* cnt;               // [NN]
    int* slots;             // [NN][CAP]
};

static __device__ __forceinline__ void accum8(float* a, uint4 v) {
    a[0] += bflo(v.x); a[1] += bfhi(v.x);
    a[2] += bflo(v.y); a[3] += bfhi(v.y);
    a[4] += bflo(v.z); a[5] += bfhi(v.z);
    a[6] += bflo(v.w); a[7] += bfhi(v.w);
}
static __device__ __forceinline__ void accum8n(float* a, uint4 v,
                                               const float* sc, const float* sh) {
    a[0] += fmaxf(bflo(v.x) * sc[0] + sh[0], 0.f);
    a[1] += fmaxf(bfhi(v.x) * sc[1] + sh[1], 0.f);
    a[2] += fmaxf(bflo(v.y) * sc[2] + sh[2], 0.f);
    a[3] += fmaxf(bfhi(v.y) * sc[3] + sh[3], 0.f);
    a[4] += fmaxf(bflo(v.z) * sc[4] + sh[4], 0.f);
    a[5] += fmaxf(bfhi(v.z) * sc[5] + sh[5], 0.f);
    a[6] += fmaxf(bflo(v.w) * sc[6] + sh[6], 0.f);
    a[7] += fmaxf(bfhi(v.w) * sc[7] + sh[7], 0.f);
}

// ============================================================================
// Mega-kernel (R19): identical phase structure to R18 (which PASSED, proving
// correctness on HW), with the spill fixed. R18's counters: VGPR=64 (the
// (512,4) bound empirically caps at 64 on this toolchain -- R1's (512,4)
// kernel also reported 48-64), and FETCH/WRITE showed ~170 MB of symmetric
// scratch traffic -> everything spilled. (512,2) caps at 256 VGPR; the
// near-identical standalone phases needed ~96 (R3). Host sizes the
// cooperative grid from the occupancy query; device is grid-size-agnostic.
// ============================================================================
__global__ __launch_bounds__(BLK, 2) void k_mega(Params P) {
    cg::grid_group grid = cg::this_grid();
    __shared__ unsigned short At[32][AST];                  // 33 KB (gemm phase)
    const int t = threadIdx.x;
    const int bid = blockIdx.x;
    const int nblk = gridDim.x;
    const int gtid = bid * BLK + t;
    const int gstride = nblk * BLK;
    const int wave = t >> 6, lane = t & 63;
    const int h = lane >> 5, l = lane & 31;

    // ================= phase 0: prep (converts + zeroing) =================
    for (int g = gtid; g < NN * 64; g += gstride) {         // x -> hx bf16
        int r = g >> 6, c4 = (g & 63) * 4;
        float4 v = *(const float4*)(P.x + (size_t)r * DIM + c4);
        uint2 p; p.x = packbf(v.x, v.y); p.y = packbf(v.z, v.w);
        *(uint2*)(P.hx + (size_t)r * DIM + c4) = p;
    }
    for (int g = gtid; g < 3 * DIM * KK; g += gstride) {    // [Ws;Wn] -> wcat [n][k]
        int L = g >> 17; int i = g & 131071;
        int k = i >> 8, n = i & 255;
        const float* Ws = (L == 0) ? P.Ws0 : ((L == 1) ? P.Ws1 : P.Ws2);
        const float* Wn = (L == 0) ? P.Wn0 : ((L == 1) ? P.Wn1 : P.Wn2);
        float v = (k < DIM) ? Ws[(size_t)k * DIM + n] : Wn[(size_t)(k - DIM) * DIM + n];
        P.wcat[(size_t)L * DIM * KK + (size_t)n * KK + k] = f2bf(v);
    }
    for (int g = gtid; g < NN + 6 * DIM; g += gstride) {
        if (g < NN) P.cnt[g] = 0;
        else P.stats[g - NN] = 0.f;
    }
    grid.sync();

    // ================= phase 1: bucket build =================
    for (int e = gtid; e < EE; e += gstride) {
        int d = P.dst[e];
        int p = atomicAdd(&P.cnt[d], 1);
        if (p < CAP) P.slots[(size_t)d * CAP + p] = P.src[e];
    }
    grid.sync();

    // ================= layers =================
    for (int L = 0; L < 3; ++L) {
        const unsigned short* src = (L == 0) ? P.hx : ((L == 1) ? P.z0 : P.z1);
        unsigned short* dst = (L == 0) ? P.z0 : ((L == 1) ? P.z1 : P.z0);
        const float* gam = (L == 1) ? P.g0 : P.g1;          // L>0 only
        const float* bet = (L == 1) ? P.be0 : P.be1;
        const float* stp = P.stats + (L - 1) * 2 * DIM;     // L>0 only

        // ---- BN affine for cols l*8..l*8+7 (gather, per-edge normalize) ----
        float sc[8], sh[8];
        if (L > 0) {
#pragma unroll
            for (int i = 0; i < 8; ++i) {
                int c = l * 8 + i;
                float mu  = stp[c] * (1.0f / NN);
                float var = stp[DIM + c] * (1.0f / NN) - mu * mu;
                float k = rsqrtf(var + EPS_BN) * gam[c];
                sc[i] = k;
                sh[i] = bet[c] - mu * k;
            }
        }

        // -------- gather phase: wave-per-node, grid-stride over nodes --------
        // All __shfl in wave-uniform flow (R12 lesson: ds_bpermute from
        // inactive lanes is undefined). No early return before grid.sync.
        {
            const uint4* srcm = (const uint4*)src;
            int wid = bid * 8 + wave;
            for (int node = wid; node < NN; node += nblk * 8) {
                int cnt = P.cnt[node]; if (cnt > CAP) cnt = CAP;
                int sv = P.slots[(size_t)node * CAP + lane];
                float a[8] = {0, 0, 0, 0, 0, 0, 0, 0};
                int j = 0;                                  // UNIFORM loop var
                for (; j + 15 < cnt; j += 16) {             // 8 loads/half in flight
                    int r0 = __shfl(sv, j +  0 + h), r1 = __shfl(sv, j +  2 + h);
                    int r2 = __shfl(sv, j +  4 + h), r3 = __shfl(sv, j +  6 + h);
                    int r4 = __shfl(sv, j +  8 + h), r5 = __shfl(sv, j + 10 + h);
                    int r6 = __shfl(sv, j + 12 + h), r7 = __shfl(sv, j + 14 + h);
                    uint4 v0 = srcm[(size_t)r0 * 32 + l];
                    uint4 v1 = srcm[(size_t)r1 * 32 + l];
                    uint4 v2 = srcm[(size_t)r2 * 32 + l];
                    uint4 v3 = srcm[(size_t)r3 * 32 + l];
                    uint4 v4 = srcm[(size_t)r4 * 32 + l];
                    uint4 v5 = srcm[(size_t)r5 * 32 + l];
                    uint4 v6 = srcm[(size_t)r6 * 32 + l];
                    uint4 v7 = srcm[(size_t)r7 * 32 + l];
                    if (L == 0) {
                        accum8(a, v0); accum8(a, v1); accum8(a, v2); accum8(a, v3);
                        accum8(a, v4); accum8(a, v5); accum8(a, v6); accum8(a, v7);
                    } else {
                        accum8n(a, v0, sc, sh); accum8n(a, v1, sc, sh);
                        accum8n(a, v2, sc, sh); accum8n(a, v3, sc, sh);
                        accum8n(a, v4, sc, sh); accum8n(a, v5, sc, sh);
                        accum8n(a, v6, sc, sh); accum8n(a, v7, sc, sh);
                    }
                }
                for (; j + 3 < cnt; j += 4) {
                    int r0 = __shfl(sv, j + h), r1 = __shfl(sv, j + 2 + h);
                    uint4 v0 = srcm[(size_t)r0 * 32 + l];
                    uint4 v1 = srcm[(size_t)r1 * 32 + l];
                    if (L == 0) { accum8(a, v0); accum8(a, v1); }
                    else { accum8n(a, v0, sc, sh); accum8n(a, v1, sc, sh); }
                }
                for (; j + 1 < cnt; j += 2) {
                    int r0 = __shfl(sv, j + h);
                    uint4 v0 = srcm[(size_t)r0 * 32 + l];
                    if (L == 0) accum8(a, v0); else accum8n(a, v0, sc, sh);
                }
                if (j < cnt) {                              // odd leftover, uniform shfl
                    int r0 = __shfl(sv, cnt - 1);
                    uint4 v0 = srcm[(size_t)r0 * 32 + l];
                    if (h == 0) {
                        if (L == 0) accum8(a, v0); else accum8n(a, v0, sc, sh);
                    }
                }
#pragma unroll
                for (int q = 0; q < 8; ++q) a[q] += __shfl_xor(a[q], 32);
                if (h == 0) {
                    float inv = 1.0f / (float)(cnt > 1 ? cnt : 1);
                    uint4 o;
                    o.x = packbf(a[0] * inv, a[1] * inv);
                    o.y = packbf(a[2] * inv, a[3] * inv);
                    o.z = packbf(a[4] * inv, a[5] * inv);
                    o.w = packbf(a[6] * inv, a[7] * inv);
                    ((uint4*)P.magg)[(size_t)node * 32 + l] = o;
                }
            }
        }
        grid.sync();

        // -------- gemm phase: 313 tiles of 32 rows, grid-stride --------
        {
            int cgS = t & 31, rs = t >> 5;                  // col-group, row-slot
            float scg[8], shg[8];
            if (L > 0) {
#pragma unroll
                for (int i = 0; i < 8; ++i) {
                    int c = cgS * 8 + i;
                    float mu  = stp[c] * (1.0f / NN);
                    float var = stp[DIM + c] * (1.0f / NN) - mu * mu;
                    float k = rsqrtf(var + EPS_BN) * gam[c];
                    scg[i] = k;
                    shg[i] = bet[c] - mu * k;
                }
            }
            const unsigned short* wcatL = P.wcat + (size_t)L * DIM * KK;
            float* statsL = P.stats + L * 2 * DIM;
            for (int tile = bid; tile < 313; tile += nblk) {
                // ---- stage A-tile: thread = (row-slot rs, 8-col group cgS) ----
#pragma unroll
                for (int rr = 0; rr < 2; ++rr) {
                    int r = rs + rr * 16;
                    int node = tile * 32 + r;
                    unsigned short* arow = &At[r][0];
                    if (node < NN) {
                        uint4 ov = *(const uint4*)(src + (size_t)node * DIM + cgS * 8);
                        if (L > 0) {
                            uint4 o;
                            o.x = packbf(fmaxf(bflo(ov.x) * scg[0] + shg[0], 0.f),
                                         fmaxf(bfhi(ov.x) * scg[1] + shg[1], 0.f));
                            o.y = packbf(fmaxf(bflo(ov.y) * scg[2] + shg[2], 0.f),
                                         fmaxf(bfhi(ov.y) * scg[3] + shg[3], 0.f));
                            o.z = packbf(fmaxf(bflo(ov.z) * scg[4] + shg[4], 0.f),
                                         fmaxf(bfhi(ov.z) * scg[5] + shg[5], 0.f));
                            o.w = packbf(fmaxf(bflo(ov.w) * scg[6] + shg[6], 0.f),
                                         fmaxf(bfhi(ov.w) * scg[7] + shg[7], 0.f));
                            ov = o;
                        }
                        *(uint2*)(arow + cgS * 8)     = make_uint2(ov.x, ov.y);
                        *(uint2*)(arow + cgS * 8 + 4) = make_uint2(ov.z, ov.w);
                        uint4 mv = *(const uint4*)(P.magg + (size_t)node * DIM + cgS * 8);
                        *(uint2*)(arow + 256 + cgS * 8)     = make_uint2(mv.x, mv.y);
                        *(uint2*)(arow + 256 + cgS * 8 + 4) = make_uint2(mv.z, mv.w);
                    } else {
                        uint2 z2 = make_uint2(0u, 0u);
                        *(uint2*)(arow + cgS * 8)           = z2;
                        *(uint2*)(arow + cgS * 8 + 4)       = z2;
                        *(uint2*)(arow + 256 + cgS * 8)     = z2;
                        *(uint2*)(arow + 256 + cgS * 8 + 4) = z2;
                    }
                }
                __syncthreads();
                // ---- phase B: one 32x32x16 MFMA chain per wave ----
                int m = l;
                int row0 = tile * 32;
                int colw0 = wave * 32;                      // 8 waves x 32 = 256 cols
                const unsigned short* Bp = wcatL + (size_t)(colw0 + m) * KK + h * 8;
                const unsigned short* Arow = &At[m][0];
                f32x16 acc;
#pragma unroll
                for (int i = 0; i < 16; ++i) acc[i] = 0.f;
#pragma unroll 8
                for (int k0 = 0; k0 < KK; k0 += 16) {
                    U16 ua;
                    ua.u2[0] = *(const uint2*)(Arow + k0 + h * 8);
                    ua.u2[1] = *(const uint2*)(Arow + k0 + h * 8 + 4);
                    bf16x8 av = ua.v;
                    bf16x8 bv = *(const bf16x8*)(Bp + k0);
                    acc = __builtin_amdgcn_mfma_f32_32x32x16_bf16(av, bv, acc, 0, 0, 0);
                }
                int cc = colw0 + m;
                float s = 0.f, s2 = 0.f;
#pragma unroll
                for (int reg = 0; reg < 16; ++reg) {
                    int r = row0 + (reg & 3) + 8 * (reg >> 2) + 4 * h;
                    if (r < NN) {
                        float v = acc[reg];
                        dst[(size_t)r * DIM + cc] = f2bf(v);
                        s += v; s2 += v * v;
                    }
                }
                s  += __shfl_down(s, 32);
                s2 += __shfl_down(s2, 32);
                if (h == 0) {
                    atomicAdd(&statsL[cc], s);
                    atomicAdd(&statsL[DIM + cc], s2);
                }
                __syncthreads();                            // LDS safe for next tile
            }
        }
        grid.sync();
    }

    // ================= final: BN + sigmoid -> out (fp32) =================
    {
        const float* statsL = P.stats + 2 * 2 * DIM;
        for (int g = gtid; g < NN * 32; g += gstride) {
            int r = g >> 5, c8 = (g & 31) * 8;
            float f[8];
            uint4 v = *(const uint4*)(P.z0 + (size_t)r * DIM + c8);
            f[0] = bflo(v.x); f[1] = bfhi(v.x); f[2] = bflo(v.y); f[3] = bfhi(v.y);
            f[4] = bflo(v.z); f[5] = bfhi(v.z); f[6] = bflo(v.w); f[7] = bfhi(v.w);
#pragma unroll
            for (int i = 0; i < 8; ++i) {
                int c = c8 + i;
                float mu  = statsL[c] * (1.0f / NN);
                float var = statsL[DIM + c] * (1.0f / NN) - mu * mu;
                float k = rsqrtf(var + EPS_BN) * P.g2[c];
                float z = f[i] * k + (P.be2[c] - mu * k);
                f[i] = 1.0f / (1.0f + __expf(-z));
            }
            float4 o0 = make_float4(f[0], f[1], f[2], f[3]);
            float4 o1 = make_float4(f[4], f[5], f[6], f[7]);
            *(float4*)(P.out + (size_t)r * DIM + c8)     = o0;
            *(float4*)(P.out + (size_t)r * DIM + c8 + 4) = o1;
        }
    }
}

// ============================================================================
// Fallback pipeline (verbatim R15, passed at 220.0 us / absmax 0.0078):
// used if the cooperative launch is rejected.
// ============================================================================
__global__ __launch_bounds__(256) void k_prep(Params P) {
    int g0 = blockIdx.x * 256 + threadIdx.x;
    int stride = gridDim.x * 256;
    for (int g = g0; g < NN * 64; g += stride) {
        int r = g >> 6, c4 = (g & 63) * 4;
        float4 v = *(const float4*)(P.x + (size_t)r * DIM + c4);
        uint2 p; p.x = packbf(v.x, v.y); p.y = packbf(v.z, v.w);
        *(uint2*)(P.hx + (size_t)r * DIM + c4) = p;
    }
    for (int g = g0; g < 3 * DIM * KK; g += stride) {
        int L = g >> 17; int i = g & 131071;
        int k = i >> 8, n = i & 255;
        const float* Ws = (L == 0) ? P.Ws0 : ((L == 1) ? P.Ws1 : P.Ws2);
        const float* Wn = (L == 0) ? P.Wn0 : ((L == 1) ? P.Wn1 : P.Wn2);
        float v = (k < DIM) ? Ws[(size_t)k * DIM + n] : Wn[(size_t)(k - DIM) * DIM + n];
        P.wcat[(size_t)L * DIM * KK + (size_t)n * KK + k] = f2bf(v);
    }
    for (int g = g0; g < NN + 6 * DIM; g += stride) {
        if (g < NN) P.cnt[g] = 0;
        else P.stats[g - NN] = 0.f;
    }
}

__global__ __launch_bounds__(256) void k_bucket(Params P) {
    int e = blockIdx.x * 256 + threadIdx.x;
    if (e < EE) {
        int d = P.dst[e];
        int p = atomicAdd(&P.cnt[d], 1);
        if (p < CAP) P.slots[(size_t)d * CAP + p] = P.src[e];
    }
}

__global__ __launch_bounds__(256) void k_pre(Params P, int Lprev,
                                             const unsigned short* __restrict__ z,
                                             unsigned short* __restrict__ hn) {
    const float* st  = P.stats + Lprev * 2 * DIM;
    const float* gam = (Lprev == 0) ? P.g0 : P.g1;
    const float* bet = (Lprev == 0) ? P.be0 : P.be1;
    int t = threadIdx.x;
    int c8 = (t & 31) * 8;
    int r = blockIdx.x * 8 + (t >> 5);
    float sc[8], sh[8];
#pragma unroll
    for (int i = 0; i < 8; ++i) {
        int c = c8 + i;
        float mu  = st[c] * (1.0f / NN);
        float var = st[DIM + c] * (1.0f / NN) - mu * mu;
        float k = rsqrtf(var + EPS_BN) * gam[c];
        sc[i] = k;
        sh[i] = bet[c] - mu * k;
    }
    uint4 v = *(const uint4*)(z + (size_t)r * DIM + c8);
    uint4 o;
    o.x = packbf(fmaxf(bflo(v.x) * sc[0] + sh[0], 0.f),
                 fmaxf(bfhi(v.x) * sc[1] + sh[1], 0.f));
    o.y = packbf(fmaxf(bflo(v.y) * sc[2] + sh[2], 0.f),
                 fmaxf(bfhi(v.y) * sc[3] + sh[3], 0.f));
    o.z = packbf(fmaxf(bflo(v.z) * sc[4] + sh[4], 0.f),
                 fmaxf(bfhi(v.z) * sc[5] + sh[5], 0.f));
    o.w = packbf(fmaxf(bflo(v.w) * sc[6] + sh[6], 0.f),
                 fmaxf(bfhi(v.w) * sc[7] + sh[7], 0.f));
    *(uint4*)(hn + (size_t)r * DIM + c8) = o;
}

__global__ __launch_bounds__(256) void k_gather(Params P,
                                                const unsigned short* __restrict__ hsrc,
                                                unsigned short* __restrict__ magg) {
    int t = threadIdx.x;
    int wave = t >> 6, lane = t & 63;
    int h = lane >> 5, l = lane & 31;
    int node = blockIdx.x * 4 + wave;
    if (node >= NN) return;
    int cnt = P.cnt[node]; if (cnt > CAP) cnt = CAP;
    int sv = P.slots[(size_t)node * CAP + lane];
    const uint4* srcm = (const uint4*)hsrc;
    float a[8] = {0, 0, 0, 0, 0, 0, 0, 0};
    int j = 0;
    for (; j + 15 < cnt; j += 16) {
        int r0 = __shfl(sv, j +  0 + h), r1 = __shfl(sv, j +  2 + h);
        int r2 = __shfl(sv, j +  4 + h), r3 = __shfl(sv, j +  6 + h);
        int r4 = __shfl(sv, j +  8 + h), r5 = __shfl(sv, j + 10 + h);
        int r6 = __shfl(sv, j + 12 + h), r7 = __shfl(sv, j + 14 + h);
        uint4 v0 = srcm[(size_t)r0 * 32 + l];
        uint4 v1 = srcm[(size_t)r1 * 32 + l];
        uint4 v2 = srcm[(size_t)r2 * 32 + l];
        uint4 v3 = srcm[(size_t)r3 * 32 + l];
        uint4 v4 = srcm[(size_t)r4 * 32 + l];
        uint4 v5 = srcm[(size_t)r5 * 32 + l];
        uint4 v6 = srcm[(size_t)r6 * 32 + l];
        uint4 v7 = srcm[(size_t)r7 * 32 + l];
        accum8(a, v0); accum8(a, v1); accum8(a, v2); accum8(a, v3);
        accum8(a, v4); accum8(a, v5); accum8(a, v6); accum8(a, v7);
    }
    for (; j + 3 < cnt; j += 4) {
        int r0 = __shfl(sv, j + h), r1 = __shfl(sv, j + 2 + h);
        uint4 v0 = srcm[(size_t)r0 * 32 + l];
        uint4 v1 = srcm[(size_t)r1 * 32 + l];
        accum8(a, v0); accum8(a, v1);
    }
    for (; j + 1 < cnt; j += 2) {
        int r0 = __shfl(sv, j + h);
        uint4 v0 = srcm[(size_t)r0 * 32 + l];
        accum8(a, v0);
    }
    if (j < cnt) {
        int r0 = __shfl(sv, cnt - 1);
        uint4 v0 = srcm[(size_t)r0 * 32 + l];
        if (h == 0) accum8(a, v0);
    }
#pragma unroll
    for (int q = 0; q < 8; ++q) a[q] += __shfl_xor(a[q], 32);
    if (h == 0) {
        float inv = 1.0f / (float)(cnt > 1 ? cnt : 1);
        uint4 o;
        o.x = packbf(a[0] * inv, a[1] * inv);
        o.y = packbf(a[2] * inv, a[3] * inv);
        o.z = packbf(a[4] * inv, a[5] * inv);
        o.w = packbf(a[6] * inv, a[7] * inv);
        ((uint4*)magg)[(size_t)node * 32 + l] = o;
    }
}

__global__ __launch_bounds__(512) void k_gemm(Params P, int L,
                                              const unsigned short* __restrict__ hsrc,
                                              const unsigned short* __restrict__ magg,
                                              unsigned short* __restrict__ gdst) {
    __shared__ unsigned short At[32][AST];
    int t = threadIdx.x;
    int wave = t >> 6, lane = t & 63;
    int h = lane >> 5, l = lane & 31;
    {
        int r = t >> 4, q = t & 15;
        int node = blockIdx.x * 32 + r;
        const unsigned short* srcp = (q < 8) ? hsrc : magg;
        int c0 = (q & 7) * 32;
        unsigned short* dstp = &At[r][(q < 8 ? 0 : 256) + c0];
        if (node < NN) {
            const uint4* gp = (const uint4*)(srcp + (size_t)node * DIM + c0);
            uint4 v0 = gp[0], v1 = gp[1], v2 = gp[2], v3 = gp[3];
            *(uint2*)(dstp)      = make_uint2(v0.x, v0.y);
            *(uint2*)(dstp + 4)  = make_uint2(v0.z, v0.w);
            *(uint2*)(dstp + 8)  = make_uint2(v1.x, v1.y);
            *(uint2*)(dstp + 12) = make_uint2(v1.z, v1.w);
            *(uint2*)(dstp + 16) = make_uint2(v2.x, v2.y);
            *(uint2*)(dstp + 20) = make_uint2(v2.z, v2.w);
            *(uint2*)(dstp + 24) = make_uint2(v3.x, v3.y);
            *(uint2*)(dstp + 28) = make_uint2(v3.z, v3.w);
        } else {
            uint2 z = make_uint2(0u, 0u);
#pragma unroll
            for (int q8 = 0; q8 < 8; ++q8) *(uint2*)(dstp + q8 * 4) = z;
        }
    }
    __syncthreads();
    const unsigned short* wcatL = P.wcat + (size_t)L * DIM * KK;
    float* statsL = P.stats + L * 2 * DIM;
    int m = l;
    int row0 = blockIdx.x * 32;
    int colw0 = wave * 32;
    const unsigned short* Bp = wcatL + (size_t)(colw0 + m) * KK + h * 8;
    const unsigned short* Arow = &At[m][0];
    f32x16 acc;
#pragma unroll
    for (int i = 0; i < 16; ++i) acc[i] = 0.f;
#pragma unroll 8
    for (int k0 = 0; k0 < KK; k0 += 16) {
        U16 ua;
        ua.u2[0] = *(const uint2*)(Arow + k0 + h * 8);
        ua.u2[1] = *(const uint2*)(Arow + k0 + h * 8 + 4);
        bf16x8 av = ua.v;
        bf16x8 bv = *(const bf16x8*)(Bp + k0);
        acc = __builtin_amdgcn_mfma_f32_32x32x16_bf16(av, bv, acc, 0, 0, 0);
    }
    int cc = colw0 + m;
    float s = 0.f, s2 = 0.f;
#pragma unroll
    for (int reg = 0; reg < 16; ++reg) {
        int r = row0 + (reg & 3) + 8 * (reg >> 2) + 4 * h;
        if (r < NN) {
            float v = acc[reg];
            gdst[(size_t)r * DIM + cc] = f2bf(v);
            s += v; s2 += v * v;
        }
    }
    s  += __shfl_down(s, 32);
    s2 += __shfl_down(s2, 32);
    if (h == 0) {
        atomicAdd(&statsL[cc], s);
        atomicAdd(&statsL[DIM + cc], s2);
    }
}

__global__ __launch_bounds__(256) void k_norm(Params P) {
    const float* statsL = P.stats + 2 * 2 * DIM;
    int t = threadIdx.x;
    int c8 = (t & 31) * 8;
    int r = blockIdx.x * 8 + (t >> 5);
    float sc[8], sh[8];
#pragma unroll
    for (int i = 0; i < 8; ++i) {
        int c = c8 + i;
        float mu  = statsL[c] * (1.0f / NN);
        float var = statsL[DIM + c] * (1.0f / NN) - mu * mu;
        float k = rsqrtf(var + EPS_BN) * P.g2[c];
        sc[i] = k;
        sh[i] = P.be2[c] - mu * k;
    }
    uint4 v = *(const uint4*)(P.z0 + (size_t)r * DIM + c8);
    float f[8] = {bflo(v.x), bfhi(v.x), bflo(v.y), bfhi(v.y),
                  bflo(v.z), bfhi(v.z), bflo(v.w), bfhi(v.w)};
#pragma unroll
    for (int i = 0; i < 8; ++i) f[i] = f[i] * sc[i] + sh[i];
    float4 o0, o1;
    o0.x = 1.0f / (1.0f + __expf(-f[0]));
    o0.y = 1.0f / (1.0f + __expf(-f[1]));
    o0.z = 1.0f / (1.0f + __expf(-f[2]));
    o0.w = 1.0f / (1.0f + __expf(-f[3]));
    o1.x = 1.0f / (1.0f + __expf(-f[4]));
    o1.y = 1.0f / (1.0f + __expf(-f[5]));
    o1.z = 1.0f / (1.0f + __expf(-f[6]));
    o1.w = 1.0f / (1.0f + __expf(-f[7]));
    *(float4*)(P.out + (size_t)r * DIM + c8)     = o0;
    *(float4*)(P.out + (size_t)r * DIM + c8 + 4) = o1;
}

extern "C" void kernel_launch(void* const* d_in, const int* in_sizes, int n_in,
                              void* d_out, int out_size, void* d_ws, size_t ws_size,
                              hipStream_t stream) {
    Params P;
    P.x   = (const float*)d_in[0];
    P.src = (const int*)d_in[1];
    P.dst = (const int*)d_in[2];
    P.Ws0 = (const float*)d_in[3];  P.Wn0 = (const float*)d_in[4];
    P.g0  = (const float*)d_in[6];  P.be0 = (const float*)d_in[7];
    P.Ws1 = (const float*)d_in[8];  P.Wn1 = (const float*)d_in[9];
    P.g1  = (const float*)d_in[11]; P.be1 = (const float*)d_in[12];
    P.Ws2 = (const float*)d_in[13]; P.Wn2 = (const float*)d_in[14];
    P.g2  = (const float*)d_in[16]; P.be2 = (const float*)d_in[17];
    P.out = (float*)d_out;

    char* ws = (char*)d_ws;
    size_t off = 0;
    P.hx   = (unsigned short*)(ws + off); off += (size_t)NN * DIM * 2;       // 5.12 MB
    P.z0   = (unsigned short*)(ws + off); off += (size_t)NN * DIM * 2;       // 5.12 MB
    P.z1   = (unsigned short*)(ws + off); off += (size_t)NN * DIM * 2;       // 5.12 MB
    P.hn   = (unsigned short*)(ws + off); off += (size_t)NN * DIM * 2;       // 5.12 MB
    P.magg = (unsigned short*)(ws + off); off += (size_t)NN * DIM * 2;       // 5.12 MB
    P.wcat = (unsigned short*)(ws + off); off += (size_t)3 * DIM * KK * 2;   // 0.79 MB
    P.stats = (float*)(ws + off); off += 3 * 2 * DIM * sizeof(float);
    P.cnt   = (int*)(ws + off); off += (size_t)NN * 4; off = (off + 255) & ~(size_t)255;
    P.slots = (int*)(ws + off); off += (size_t)NN * CAP * 4;                 // 2.56 MB
    (void)ws_size;

    // ---- cooperative grid sizing: probe occupancy once (host-side, safe) ----
    static int coop_grid = -1;                 // -1 = unprobed, 0 = coop disabled
    if (coop_grid < 0) {
        int occ = 0;
        hipError_t e = hipOccupancyMaxActiveBlocksPerMultiprocessor(&occ, k_mega, BLK, 0);
        if (e != hipSuccess || occ < 1) { coop_grid = 0; (void)hipGetLastError(); }
        else coop_grid = (occ >= 2 ? 2 : 1) * 256;   // 256 CUs x blocks/CU
    }

    bool done = false;
    if (coop_grid > 0) {
        void* kargs[] = { (void*)&P };
        hipError_t e = hipLaunchCooperativeKernel(k_mega, dim3(coop_grid), dim3(BLK),
                                                  kargs, 0, stream);
        if (e == hipSuccess) done = true;
        else { (void)hipGetLastError(); coop_grid = 0; }   // disable for future calls
    }
    if (!done) {
        // R15 fallback pipeline (passed: 220 us, absmax 0.0078)
        k_prep<<<512, 256, 0, stream>>>(P);
        k_bucket<<<(EE + 255) / 256, 256, 0, stream>>>(P);
        k_gather<<<2500, 256, 0, stream>>>(P, P.hx, P.magg);
        k_gemm<<<313, 512, 0, stream>>>(P, 0, P.hx, P.magg, P.z0);
        k_pre<<<1250, 256, 0, stream>>>(P, 0, P.z0, P.hn);
        k_gather<<<2500, 256, 0, stream>>>(P, P.hn, P.magg);
        k_gemm<<<313, 512, 0, stream>>>(P, 1, P.hn, P.magg, P.z1);
        k_pre<<<1250, 256, 0, stream>>>(P, 1, P.z1, P.hn);
        k_gather<<<2500, 256, 0, stream>>>(P, P.hn, P.magg);
        k_gemm<<<313, 512, 0, stream>>>(P, 2, P.hn, P.magg, P.z0);
        k_norm<<<NN / 8, 256, 0, stream>>>(P);
    }
}